// Round 6
// baseline (886.448 us; speedup 1.0000x reference)
//
#include <hip/hip_runtime.h>

#define SEQ 64

typedef _Float16 f16;
typedef _Float16 f16x8 __attribute__((ext_vector_type(8)));
typedef _Float16 f16x2 __attribute__((ext_vector_type(2)));
typedef float f32x4 __attribute__((ext_vector_type(4)));

__device__ __forceinline__ float sig_(float x) { return 1.0f / (1.0f + __expf(-x)); }
__device__ __forceinline__ float tanh_(float x) { return 1.0f - 2.0f / (1.0f + __expf(2.0f * x)); }

template<int CTRL, int RMASK>
__device__ __forceinline__ float dpp_add(float x) {
  const int t = __builtin_amdgcn_update_dpp(0, __float_as_int(x), CTRL, RMASK, 0xF, true);
  return x + __int_as_float(t);
}
template<int CTRL>
__device__ __forceinline__ float dpp_max(float x) {
  const int t = __builtin_amdgcn_update_dpp(0, __float_as_int(x), CTRL, 0xF, 0xF, true);
  return fmaxf(x, __int_as_float(t));
}

// h state: node-major, 128 f16/row, XOR-swizzled in 8-f16 (16B) blocks
__device__ __forceinline__ int hOff(int n, int f) {
  return n * 128 + ((((f >> 3) ^ (n & 15)) << 3) | (f & 7));
}

// ---- prep: comp_W (256x640 fp32) -> f16 MFMA B-fragment order in ws ----
__global__ void prep_kernel(const float* __restrict__ cW, f16* __restrict__ wsB) {
  const int idx  = blockIdx.x * 256 + threadIdx.x;   // 0..20479
  const int kk   = idx / 2560;
  const int rem  = idx - kk * 2560;
  const int nt   = rem >> 6;
  const int lane = rem & 63;
  const int col  = nt * 16 + (lane & 15);
  const int kb   = kk * 32 + ((lane >> 4) << 3);
  f16x8 v;
  #pragma unroll
  for (int j = 0; j < 8; ++j) v[j] = (f16)cW[(kb + j) * 640 + col];
  ((f16x8*)wsB)[idx] = v;
}

__global__ __launch_bounds__(512, 2) void pyramid_kernel(
    const int*   __restrict__ sentences,
    const float* __restrict__ emb,
    const f16*   __restrict__ wsB,
    const float* __restrict__ cb, const float* __restrict__ selw, const float* __restrict__ selb,
    float* __restrict__ fin)
{
  __shared__ __align__(16) f16   hS[65 * 128];    // 16640 B
  __shared__ __align__(16) float cS[65 * 132];    // 34320 B
  __shared__ float lgp[8 * 64];                   // 2048 B
  __shared__ __align__(16) float pS[64], clS[64], crS[64];  // 768 B
  // total ~53.8 KB

  const int tid  = threadIdx.x;
  const int b    = blockIdx.x;
  const int wv   = tid >> 6;
  const int lane = tid & 63;
  const int quad = lane >> 4;
  const int l15  = lane & 15;
  const int d    = wv * 16 + l15;
  const f16x8* Bf = (const f16x8*)wsB;

  // ---- persistent B: ALL 40 frags (160 regs), pinned into AGPRs ----
  f16x8 Breg[40];
  #pragma unroll
  for (int kk = 0; kk < 8; ++kk)
    #pragma unroll
    for (int q = 0; q < 5; ++q)
      Breg[kk * 5 + q] = Bf[((kk * 40 + q * 8 + wv) << 6) + lane];
  #pragma unroll
  for (int i = 0; i < 40; ++i) asm volatile("" : "+a"(Breg[i]));  // pin to AGPR bank

  // ---- embedding gather: h -> LDS f16, c -> LDS f32 ----
  {
    const int s = tid >> 3, part = tid & 7;
    const int row = sentences[b * SEQ + s];
    const float4* er = (const float4*)(emb + (size_t)row * 256 + part * 32);
    #pragma unroll
    for (int i4 = 0; i4 < 8; ++i4) {
      const float4 v = er[i4];
      const float vv[4] = {v.x, v.y, v.z, v.w};
      #pragma unroll
      for (int c = 0; c < 4; ++c) {
        const int f = part * 32 + i4 * 4 + c;
        if (f < 128) hS[hOff(s, f)] = (f16)vv[c];
        else         cS[s * 132 + (f - 128)] = vv[c];
      }
    }
  }
  if (tid < 128) hS[64 * 128 + tid] = (f16)0.f;   // guard row (node 64)
  if (tid < 132) cS[64 * 132 + tid] = 0.f;
  __syncthreads();

  float bq[5];
  #pragma unroll
  for (int q = 0; q < 5; ++q) bq[q] = cb[q * 128 + d];
  const float swh = selw[d], swc = selw[128 + d], selbv = selb[0];

  // ---- pyramid: 63 sequential layers; zero global memory in the loop ----
  for (int W = 63; W >= 1; --W) {
    const int NMT = (W + 15) >> 4;
    f16x2 chP[4][2];     // comp_h, packed f16
    f16x2 ccP[4][2];     // comp_c, packed f16

    // ---- phase A: MFMA + gate epilogue, one mt at a time (acc reused) ----
    #pragma unroll
    for (int mt = 0; mt < 4; ++mt) if (mt < NMT) {
      f32x4 acc[5];
      #pragma unroll
      for (int q = 0; q < 5; ++q) acc[q] = (f32x4){bq[q], bq[q], bq[q], bq[q]};
      #pragma unroll
      for (int kk = 0; kk < 8; ++kk) {
        const int n   = mt * 16 + l15 + (kk >> 2);   // right half reads node n+1
        const int blk = (kk & 3) * 4 + quad;
        const f16x8 av = *(const f16x8*)&hS[n * 128 + ((blk ^ (n & 15)) << 3)];
        #pragma unroll
        for (int q = 0; q < 5; ++q)
          acc[q] = __builtin_amdgcn_mfma_f32_16x16x32_f16(av, Breg[kk * 5 + q], acc[q], 0, 0, 0);
      }
      const int n0q = mt * 16 + quad * 4;
      float c5[5];
      #pragma unroll
      for (int r = 0; r < 5; ++r) c5[r] = cS[(n0q + r) * 132 + d];
      #pragma unroll
      for (int r = 0; r < 4; ++r) {
        const float c = sig_(acc[1][r]) * c5[r] + sig_(acc[2][r]) * c5[r + 1]
                      + sig_(acc[0][r]) * tanh_(acc[3][r]);
        const float h = sig_(acc[4][r]) * tanh_(c);
        ccP[mt][r >> 1][r & 1] = (f16)c;
        chP[mt][r >> 1][r & 1] = (f16)h;
        float v = __builtin_fmaf(h, swh, c * swc);   // logit partial
        v = dpp_add<0xB1, 0xF>(v);
        v = dpp_add<0x4E, 0xF>(v);
        v = dpp_add<0x124, 0xF>(v);
        v = dpp_add<0x128, 0xF>(v);
        if (l15 == 0) {
          const int n = n0q + r;
          if (n < W) lgp[(wv << 6) + n] = v;
        }
      }
    }
    __syncthreads();

    // ---- phase B: softmax + prefix sums, redundantly per wave ----
    {
      float lg = -3.0e38f;
      if (lane < W) {
        float s = selbv;
        #pragma unroll
        for (int dg = 0; dg < 8; ++dg) s += lgp[(dg << 6) + lane];
        lg = s;
      }
      float m = lg;
      m = dpp_max<0xB1>(m); m = dpp_max<0x4E>(m);
      m = dpp_max<0x124>(m); m = dpp_max<0x128>(m);
      m = fmaxf(m, __shfl_xor(m, 16, 64));
      m = fmaxf(m, __shfl_xor(m, 32, 64));
      const float e = (lane < W) ? __expf(lg - m) : 0.f;
      float t = e;
      t = dpp_add<0xB1, 0xF>(t); t = dpp_add<0x4E, 0xF>(t);
      t = dpp_add<0x124, 0xF>(t); t = dpp_add<0x128, 0xF>(t);
      t += __shfl_xor(t, 16, 64);
      t += __shfl_xor(t, 32, 64);
      const float p = e / t;
      float cs = p;                       // inclusive scan (DPP)
      cs = dpp_add<0x111, 0xF>(cs);
      cs = dpp_add<0x112, 0xF>(cs);
      cs = dpp_add<0x114, 0xF>(cs);
      cs = dpp_add<0x118, 0xF>(cs);
      cs = dpp_add<0x142, 0xA>(cs);
      cs = dpp_add<0x143, 0xC>(cs);
      const float T = __shfl(cs, 63, 64);
      if (lane < W) {
        pS[lane]  = p;
        clS[lane] = T - cs;
        crS[lane] = cs - p;
      }
    }
    // (no barrier: each wave wrote its own redundant copy)

    // ---- phase C: blend; read-all-then-write-all per mt (R3-proven) ----
    #pragma unroll
    for (int mt = 0; mt < 4; ++mt) if (mt < NMT) {
      const int n0q = mt * 16 + quad * 4;
      const f32x4 pv  = *(const f32x4*)&pS[n0q];
      const f32x4 clv = *(const f32x4*)&clS[n0q];
      const f32x4 crv = *(const f32x4*)&crS[n0q];
      float oh[5], c5[5];
      #pragma unroll
      for (int r = 0; r < 5; ++r) {
        oh[r] = (float)hS[hOff(n0q + r, d)];
        c5[r] = cS[(n0q + r) * 132 + d];
      }
      #pragma unroll
      for (int r = 0; r < 4; ++r) {
        const int n = n0q + r;
        if (n < W) {
          const float nh = clv[r] * oh[r] + crv[r] * oh[r + 1] + pv[r] * (float)chP[mt][r >> 1][r & 1];
          const float nc = clv[r] * c5[r] + crv[r] * c5[r + 1] + pv[r] * (float)ccP[mt][r >> 1][r & 1];
          hS[hOff(n, d)] = (f16)nh;
          cS[n * 132 + d] = nc;
        }
      }
    }
    __syncthreads();
  }

  // ---- write final state[0] = [h0 || c0] ----
  if (tid < 128) {
    fin[b * 256 + tid] = (float)hS[tid];        // hOff(0,f)=f
    fin[b * 256 + 128 + tid] = cS[tid];         // cS row 0
  }
}

// ---- MLP head: weight-read-once, lane-coalesced ----
// z0: grid 32 = 16 col-groups x 2 row-halves; block computes 64 cols x 32 rows
__global__ __launch_bounds__(256) void z0_kernel(
    const float* __restrict__ fin, const float* __restrict__ w0,
    const float* __restrict__ b0, float* __restrict__ z0g)
{
  __shared__ float xl[256][33];
  const int t    = threadIdx.x;
  const int cg   = blockIdx.x >> 1, rh = blockIdx.x & 1;
  const int col  = cg * 64 + (t & 63);
  const int rg   = t >> 6;              // wave id: 8 rows each
  const int row0 = rh * 32;
  for (int idx = t; idx < 32 * 256; idx += 256) {
    const int row = idx >> 8, k = idx & 255;
    xl[k][row] = fin[(row0 + row) * 256 + k];    // coalesced over k
  }
  __syncthreads();
  float a[8];
  const float bias = b0[col];
  #pragma unroll
  for (int r = 0; r < 8; ++r) a[r] = bias;
  #pragma unroll 4
  for (int k = 0; k < 256; ++k) {
    const float w = w0[k * 1024 + col];          // coalesced over col
    #pragma unroll
    for (int r = 0; r < 8; ++r)
      a[r] = __builtin_fmaf(xl[k][rg * 8 + r], w, a[r]);  // LDS broadcast
  }
  #pragma unroll
  for (int r = 0; r < 8; ++r)
    z0g[(row0 + rg * 8 + r) * 1024 + col] = fmaxf(a[r], 0.f);
}

// z1: same structure, k chunked 4x256; writes TRANSPOSED z1T[col][row]
__global__ __launch_bounds__(256) void z1_kernel(
    const float* __restrict__ z0g, const float* __restrict__ w1,
    const float* __restrict__ b1, float* __restrict__ z1T)
{
  __shared__ float zl[256][33];
  const int t    = threadIdx.x;
  const int cg   = blockIdx.x >> 1, rh = blockIdx.x & 1;
  const int col  = cg * 64 + (t & 63);
  const int rg   = t >> 6;
  const int row0 = rh * 32;
  float a[8];
  const float bias = b1[col];
  #pragma unroll
  for (int r = 0; r < 8; ++r) a[r] = bias;
  for (int k0 = 0; k0 < 1024; k0 += 256) {
    __syncthreads();
    for (int idx = t; idx < 32 * 256; idx += 256) {
      const int row = idx >> 8, kc = idx & 255;
      zl[kc][row] = z0g[(row0 + row) * 1024 + k0 + kc];   // coalesced over kc
    }
    __syncthreads();
    #pragma unroll 4
    for (int kc = 0; kc < 256; ++kc) {
      const float w = w1[(k0 + kc) * 1024 + col];         // coalesced over col
      #pragma unroll
      for (int r = 0; r < 8; ++r)
        a[r] = __builtin_fmaf(zl[kc][rg * 8 + r], w, a[r]);
    }
  }
  #pragma unroll
  for (int r = 0; r < 8; ++r)
    z1T[col * 64 + row0 + rg * 8 + r] = fmaxf(a[r], 0.f);
}

__global__ __launch_bounds__(192) void out_kernel(
    const float* __restrict__ z1T, const float* __restrict__ cwt,
    const float* __restrict__ cbias, float* __restrict__ out)
{
  const int t = threadIdx.x;            // 192 = 3 cls x 64 rows
  const int row = t & 63, cls = t >> 6;
  float a = cbias[cls];
  #pragma unroll 8
  for (int k = 0; k < 1024; ++k)
    a = __builtin_fmaf(z1T[k * 64 + row], cwt[k * 3 + cls], a);  // coalesced over row
  out[row * 3 + cls] = a;
}

extern "C" void kernel_launch(void* const* d_in, const int* in_sizes, int n_in,
                              void* d_out, int out_size, void* d_ws, size_t ws_size,
                              hipStream_t stream) {
  (void)in_sizes; (void)n_in; (void)out_size; (void)ws_size;
  f16*   wsB = (f16*)d_ws;                               // 409600 B
  float* fin = (float*)((char*)d_ws + 409600);           // 65536 B
  float* z0g = (float*)((char*)d_ws + 409600 + 65536);   // 262144 B
  float* z1T = (float*)((char*)d_ws + 409600 + 65536 + 262144);  // 262144 B

  prep_kernel<<<dim3(80), dim3(256), 0, stream>>>((const float*)d_in[3], wsB);
  pyramid_kernel<<<dim3(64), dim3(512), 0, stream>>>(
      (const int*)d_in[0], (const float*)d_in[2], wsB,
      (const float*)d_in[4], (const float*)d_in[5], (const float*)d_in[6], fin);
  z0_kernel<<<dim3(32), dim3(256), 0, stream>>>(
      fin, (const float*)d_in[7], (const float*)d_in[8], z0g);
  z1_kernel<<<dim3(32), dim3(256), 0, stream>>>(
      z0g, (const float*)d_in[9], (const float*)d_in[10], z1T);
  out_kernel<<<dim3(1), dim3(192), 0, stream>>>(
      z1T, (const float*)d_in[11], (const float*)d_in[12], (float*)d_out);
}